// Round 10
// baseline (102.061 us; speedup 1.0000x reference)
//
#include <hip/hip_runtime.h>
#include <stdint.h>

// FusedFP4Linear: out = gelu(x @ dequant(w_fp4)^T + bias)
// M=128, K=4096, N=16384. Weights [N, K/2] int32, low byte = two FP4 nibbles
// (hi nibble = even k, lo nibble = odd k).
// R10: ZERO-barrier direct-register GEMM. No LDS staging: each wave loads
// its own A-frags (bf16x8 from ws-converted x) and B-frags (uint4 packed
// int32 -> in-register v_perm decode) straight from L2/L3. 4-stage register
// pipeline (load k+4 after compute k => ~3-tile latency cover), no s_barrier
// in the main loop, waves fully independent. R7-verified fragment mapping,
// intra-block k-split (8 waves = 4 pos x 2 k-halves) + end LDS reduce.

#define M_DIM 128
#define K_DIM 4096
#define N_DIM 16384
#define NT    512              // 8 waves
#define NBLK  256

typedef __attribute__((ext_vector_type(8))) __bf16 bf16x8;
typedef __attribute__((ext_vector_type(4))) float  f32x4;
typedef unsigned short ushort_t;

__device__ __forceinline__ unsigned f2b_bits(float f) {
  unsigned u = __builtin_bit_cast(unsigned, f);
  u += 0x7FFFu + ((u >> 16) & 1u);   // RNE
  return u >> 16;
}

__global__ __launch_bounds__(256) void convert_x_kernel(
    const float* __restrict__ x, ushort_t* __restrict__ xb) {
  int i = (blockIdx.x * blockDim.x + threadIdx.x) * 4;
  float4 v = *(const float4*)(x + i);
  ushort4 p;
  p.x = (ushort_t)f2b_bits(v.x);
  p.y = (ushort_t)f2b_bits(v.y);
  p.z = (ushort_t)f2b_bits(v.z);
  p.w = (ushort_t)f2b_bits(v.w);
  *(ushort4*)(xb + i) = p;
}

// 4 packed int32 (low bytes) -> 8 bf16 (k-order: b0.hi, b0.lo, b1.hi, ...)
__device__ __forceinline__ bf16x8 decode8(uint4 p) {
  unsigned u01 = __builtin_amdgcn_perm(p.y, p.x, 0x04000400u);
  unsigned u23 = __builtin_amdgcn_perm(p.w, p.z, 0x04000400u);
  unsigned q   = __builtin_amdgcn_perm(u23, u01, 0x05040100u);  // [x0,y0,z0,w0]
  unsigned e  = (q >> 4) & 0x0F0F0F0Fu;
  unsigned o  = q & 0x0F0F0F0Fu;
  unsigned em = e & 0x07070707u, om = o & 0x07070707u;
  unsigned elo = __builtin_amdgcn_perm(0xC0804000u, 0xC0800000u, em);
  unsigned ehi = __builtin_amdgcn_perm(0x40404040u, 0x3F3F3F00u, em);
  unsigned olo = __builtin_amdgcn_perm(0xC0804000u, 0xC0800000u, om);
  unsigned ohi = __builtin_amdgcn_perm(0x40404040u, 0x3F3F3F00u, om);
  ehi |= (e & 0x08080808u) << 4;
  ohi |= (o & 0x08080808u) << 4;
  unsigned t0 = __builtin_amdgcn_perm(ehi, elo, 0x05010400u);
  unsigned t1 = __builtin_amdgcn_perm(ohi, olo, 0x05010400u);
  unsigned t2 = __builtin_amdgcn_perm(ehi, elo, 0x07030602u);
  unsigned t3 = __builtin_amdgcn_perm(ohi, olo, 0x07030602u);
  uint4 r;
  r.x = __builtin_amdgcn_perm(t1, t0, 0x05040100u);
  r.y = __builtin_amdgcn_perm(t1, t0, 0x07060302u);
  r.z = __builtin_amdgcn_perm(t3, t2, 0x05040100u);
  r.w = __builtin_amdgcn_perm(t3, t2, 0x07060302u);
  return __builtin_bit_cast(bf16x8, r);
}

#define MFMA16(a_, b_, c_) __builtin_amdgcn_mfma_f32_16x16x32_bf16(a_, b_, c_, 0, 0, 0)

__global__ __launch_bounds__(NT) void fp4gemm_direct_kernel(
    const ushort_t* __restrict__ xsrc,    // bf16 x [128,4096] (ws)
    const int*  __restrict__ wq,          // [N, K/2] packed
    const float* __restrict__ scale,      // [N]
    const float* __restrict__ bias,       // [N]
    float* __restrict__ out) {            // [M, N]
  __shared__ __align__(16) uint8_t lds[32768];   // end-reduce only

  const int t   = threadIdx.x;
  const int w   = t >> 6;                 // wave 0..7
  const int l   = t & 63;
  const int l16 = l & 15;
  const int lq  = l >> 4;
  const int kh  = w >> 2;                 // k-half 0..1 (32-wide k slice)
  const int mh  = (w >> 1) & 1;           // m-half: rows mh*64..+63
  const int nh  = w & 1;                  // n-half: cols nh*32..+31

  // bijective XCD n-chunk swizzle (256 % 8 == 0)
  const int bid = blockIdx.x;
  const int n0  = ((bid & 7) * 32 + (bid >> 3)) * 64;

  // per-lane fragment base addresses (R7-verified mapping)
  //   A frag r: row mh*64 + r*16 + l16, k = kt*64 + kh*32 + lq*8  (8 bf16)
  //   B frag c: row n0 + nh*32 + c*16 + l16, same k (8 k = 4 ints = 16B)
  const uint8_t* aB = (const uint8_t*)xsrc +
      (size_t)(mh * 64 + l16) * 8192 + kh * 64 + lq * 16;
  const uint8_t* bB = (const uint8_t*)wq +
      (size_t)(n0 + nh * 32 + l16) * 8192 + kh * 64 + lq * 16;

  f32x4 acc[4][2] = {{{0,0,0,0},{0,0,0,0}},{{0,0,0,0},{0,0,0,0}},
                     {{0,0,0,0},{0,0,0,0}},{{0,0,0,0},{0,0,0,0}}};

  uint4 sa0[4], sa1[4], sa2[4], sa3[4];   // A stages (tiles kt%4)
  uint4 sb0[2], sb1[2], sb2[2], sb3[2];   // B stages

#define LOAD(kt_, s_) do { \
  _Pragma("unroll") \
  for (int r_ = 0; r_ < 4; ++r_) \
    sa##s_[r_] = *(const uint4*)(aB + (size_t)r_ * 131072 + (kt_) * 128); \
  _Pragma("unroll") \
  for (int c_ = 0; c_ < 2; ++c_) \
    sb##s_[c_] = *(const uint4*)(bB + (size_t)c_ * 131072 + (kt_) * 128); \
} while (0)

#define COMP(s_) do { \
  bf16x8 pb0_ = decode8(sb##s_[0]); \
  bf16x8 pb1_ = decode8(sb##s_[1]); \
  _Pragma("unroll") \
  for (int r_ = 0; r_ < 4; ++r_) { \
    bf16x8 ar_ = __builtin_bit_cast(bf16x8, sa##s_[r_]); \
    acc[r_][0] = MFMA16(ar_, pb0_, acc[r_][0]); \
    acc[r_][1] = MFMA16(ar_, pb1_, acc[r_][1]); \
  } \
} while (0)

  LOAD(0, 0); LOAD(1, 1); LOAD(2, 2); LOAD(3, 3);
  for (int kt = 0; kt < 60; kt += 4) {
    COMP(0); LOAD(kt + 4, 0);
    COMP(1); LOAD(kt + 5, 1);
    COMP(2); LOAD(kt + 6, 2);
    COMP(3); LOAD(kt + 7, 3);
  }
  COMP(0); COMP(1); COMP(2); COMP(3);     // tiles 60..63

  // ---- cross-wave k-reduce (pairs w, w+4 share output position w&3) ----
  __syncthreads();
  {
    uint8_t* red = lds;
    const int pos = w & 3;
    if (w >= 4) {
#pragma unroll
      for (int r = 0; r < 4; ++r)
#pragma unroll
        for (int c = 0; c < 2; ++c)
          *(f32x4*)(red + pos * 8192 + (r * 2 + c) * 1024 + l * 16) = acc[r][c];
    }
    __syncthreads();
    if (w < 4) {
#pragma unroll
      for (int r = 0; r < 4; ++r)
#pragma unroll
        for (int c = 0; c < 2; ++c)
          acc[r][c] += *(const f32x4*)(red + pos * 8192 + (r * 2 + c) * 1024 + l * 16);

      // ---- epilogue: scale, bias, exact GELU ----
#pragma unroll
      for (int c = 0; c < 2; ++c) {
        const int ngc = n0 + nh * 32 + c * 16 + l16;
        const float s  = scale[ngc];
        const float bb = bias[ngc];
#pragma unroll
        for (int r = 0; r < 4; ++r) {
#pragma unroll
          for (int j = 0; j < 4; ++j) {
            int m = mh * 64 + r * 16 + lq * 4 + j;
            float y = acc[r][c][j] * s + bb;
            float g = 0.5f * y * (1.0f + erff(y * 0.70710678118654752f));
            out[(size_t)m * N_DIM + ngc] = g;
          }
        }
      }
    }
  }
#undef LOAD
#undef COMP
}

// Fallback (ws too small): full-K, fp32-x inline, simple 2-buffer pipeline.
__global__ __launch_bounds__(NT) void fp4gemm_fallback_kernel(
    const float* __restrict__ x, const int* __restrict__ wq,
    const float* __restrict__ scale, const float* __restrict__ bias,
    float* __restrict__ out) {
  __shared__ __align__(16) uint8_t lds[49152];
  const int t = threadIdx.x, w = t >> 6, l = t & 63;
  const int l16 = l & 15, lq = l >> 4, mq = w >> 1, nh = w & 1;
  const int n0 = (int)blockIdx.x * 64;
  const int srow = t >> 3, scol = (t & 7) * 16, sswz = (srow & 7) << 4;
  const int bwr = srow * 128 + (scol ^ sswz);
  const uint8_t* wqb = (const uint8_t*)wq;
  f32x4 acc00 = {0,0,0,0}, acc01 = {0,0,0,0};
  f32x4 acc10 = {0,0,0,0}, acc11 = {0,0,0,0};
  const int aR0 = (mq * 32 + l16) * 128;
  const int bR0 = (nh * 32 + l16) * 128;
  const int cB  = (lq << 4) ^ ((l16 & 7) << 4);
  for (int kt = 0; kt < 64; ++kt) {
    __syncthreads();
    int bb = kt & 1;
#pragma unroll
    for (int i = 0; i < 2; ++i) {
      const float* xf = x + (size_t)(i * 64 + srow) * K_DIM + (size_t)kt * 64 + (scol >> 1);
      float4 v0 = *(const float4*)(xf);
      float4 v1 = *(const float4*)(xf + 4);
      uint4 pk = make_uint4(f2b_bits(v0.x) | (f2b_bits(v0.y) << 16),
                            f2b_bits(v0.z) | (f2b_bits(v0.w) << 16),
                            f2b_bits(v1.x) | (f2b_bits(v1.y) << 16),
                            f2b_bits(v1.z) | (f2b_bits(v1.w) << 16));
      *(uint4*)(lds + bb * 16384 + (size_t)(i * 64 + srow) * 128 + (scol ^ sswz)) = pk;
    }
    {
      uint4 pv = *(const uint4*)(wqb + (size_t)(n0 + srow) * 8192 + (size_t)kt * 128 + scol);
      *(bf16x8*)(lds + 32768 + bb * 8192 + bwr) = decode8(pv);
    }
    __syncthreads();
    {
      const uint8_t* Ab_ = lds + bb * 16384;
      const uint8_t* Bb_ = lds + 32768 + bb * 8192;
#pragma unroll
      for (int ks = 0; ks < 2; ++ks) {
        const int cS = (ks << 6) ^ cB;
        bf16x8 a0 = *(const bf16x8*)(Ab_ + aR0 + cS);
        bf16x8 a1 = *(const bf16x8*)(Ab_ + aR0 + 2048 + cS);
        bf16x8 b0 = *(const bf16x8*)(Bb_ + bR0 + cS);
        bf16x8 b1 = *(const bf16x8*)(Bb_ + bR0 + 2048 + cS);
        acc00 = MFMA16(a0, b0, acc00);
        acc01 = MFMA16(a0, b1, acc01);
        acc10 = MFMA16(a1, b0, acc10);
        acc11 = MFMA16(a1, b1, acc11);
      }
    }
  }
#pragma unroll
  for (int c = 0; c < 2; ++c) {
    const int ngc = n0 + nh * 32 + c * 16 + l16;
    const float s = scale[ngc];
    const float bv = bias[ngc];
    f32x4 v0 = c ? acc01 : acc00;
    f32x4 v1 = c ? acc11 : acc10;
#pragma unroll
    for (int fr = 0; fr < 2; ++fr) {
      f32x4 vv = fr ? v1 : v0;
#pragma unroll
      for (int j = 0; j < 4; ++j) {
        int m = mq * 32 + fr * 16 + lq * 4 + j;
        float y = vv[j] * s + bv;
        out[(size_t)m * N_DIM + ngc] =
            0.5f * y * (1.0f + erff(y * 0.70710678118654752f));
      }
    }
  }
}

extern "C" void kernel_launch(void* const* d_in, const int* in_sizes, int n_in,
                              void* d_out, int out_size, void* d_ws, size_t ws_size,
                              hipStream_t stream) {
  const float* x     = (const float*)d_in[0];
  const int*   wq    = (const int*)d_in[1];
  const float* scale = (const float*)d_in[2];
  const float* bias  = (const float*)d_in[3];
  float* out = (float*)d_out;

  const size_t xb_bytes = (size_t)M_DIM * K_DIM * 2;   // 1 MB
  if (ws_size >= xb_bytes) {
    ushort_t* xb = (ushort_t*)d_ws;
    convert_x_kernel<<<(M_DIM * K_DIM) / (256 * 4), 256, 0, stream>>>(x, xb);
    fp4gemm_direct_kernel<<<NBLK, NT, 0, stream>>>(xb, wq, scale, bias, out);
  } else {
    fp4gemm_fallback_kernel<<<N_DIM / 64, NT, 0, stream>>>(
        x, wq, scale, bias, out);
  }
}

// Round 11
// 57.290 us; speedup vs baseline: 1.7815x; 1.7815x over previous
//
#include <hip/hip_runtime.h>
#include <stdint.h>

// FusedFP4Linear: out = gelu(x @ dequant(w_fp4)^T + bias)
// M=128, K=4096, N=16384. Weights [N, K/2] int32, low byte = two FP4 nibbles
// (hi nibble = even k, lo nibble = odd k).
// R11: dual full-K chains. Block = 128x32 out, 4 waves, full K. B kept
// PACKED-COMPACT in LDS (pack4 at staging, decode4 in compute): LDS = 68KB
// -> 2 blocks/CU = two independent barrier chains (the only lever that ever
// helped: R3, R9). Phase = 2 k-tiles (32 barriers, halved). gl16 A staging
// (pre-swizzled source), counted-wait schedule with 1-phase prefetch depth.

#define M_DIM 128
#define K_DIM 4096
#define N_DIM 16384
#define NT    256              // 4 waves
#define NBLK  512              // 512 n-tiles of 32

#define ABASE(c) ((c)*32768)             // 2 x 32KB A phase-bufs (2 tiles each)
#define BBASE(c) (65536 + (c)*2048)      // 2 x 2KB compact-B phase-bufs
#define LDS_SZ   69632                   // -> 2 blocks/CU

typedef __attribute__((ext_vector_type(8))) __bf16 bf16x8;
typedef __attribute__((ext_vector_type(4))) float  f32x4;
typedef unsigned short ushort_t;

__device__ __forceinline__ unsigned f2b_bits(float f) {
  unsigned u = __builtin_bit_cast(unsigned, f);
  u += 0x7FFFu + ((u >> 16) & 1u);   // RNE
  return u >> 16;
}

__global__ __launch_bounds__(256) void convert_x_kernel(
    const float* __restrict__ x, ushort_t* __restrict__ xb) {
  int i = (blockIdx.x * blockDim.x + threadIdx.x) * 4;
  float4 v = *(const float4*)(x + i);
  ushort4 p;
  p.x = (ushort_t)f2b_bits(v.x);
  p.y = (ushort_t)f2b_bits(v.y);
  p.z = (ushort_t)f2b_bits(v.z);
  p.w = (ushort_t)f2b_bits(v.w);
  *(ushort4*)(xb + i) = p;
}

__device__ __forceinline__ void gl16(const void* g, void* l) {
  __builtin_amdgcn_global_load_lds(
      (const __attribute__((address_space(1))) void*)g,
      (__attribute__((address_space(3))) void*)l, 16, 0, 0);
}

// low bytes of 4 ints -> 4 packed bytes
__device__ __forceinline__ unsigned pack4(uint4 p) {
  unsigned u01 = __builtin_amdgcn_perm(p.y, p.x, 0x04000400u);
  unsigned u23 = __builtin_amdgcn_perm(p.w, p.z, 0x04000400u);
  return __builtin_amdgcn_perm(u23, u01, 0x05040100u);   // [x0,y0,z0,w0]
}

// 4 packed bytes -> 8 bf16 (k-order: b0.hi, b0.lo, b1.hi, ...) [R6-verified]
__device__ __forceinline__ bf16x8 decode4(unsigned q) {
  unsigned e  = (q >> 4) & 0x0F0F0F0Fu;
  unsigned o  = q & 0x0F0F0F0Fu;
  unsigned em = e & 0x07070707u, om = o & 0x07070707u;
  unsigned elo = __builtin_amdgcn_perm(0xC0804000u, 0xC0800000u, em);
  unsigned ehi = __builtin_amdgcn_perm(0x40404040u, 0x3F3F3F00u, em);
  unsigned olo = __builtin_amdgcn_perm(0xC0804000u, 0xC0800000u, om);
  unsigned ohi = __builtin_amdgcn_perm(0x40404040u, 0x3F3F3F00u, om);
  ehi |= (e & 0x08080808u) << 4;
  ohi |= (o & 0x08080808u) << 4;
  unsigned t0 = __builtin_amdgcn_perm(ehi, elo, 0x05010400u);
  unsigned t1 = __builtin_amdgcn_perm(ohi, olo, 0x05010400u);
  unsigned t2 = __builtin_amdgcn_perm(ehi, elo, 0x07030602u);
  unsigned t3 = __builtin_amdgcn_perm(ohi, olo, 0x07030602u);
  uint4 r;
  r.x = __builtin_amdgcn_perm(t1, t0, 0x05040100u);
  r.y = __builtin_amdgcn_perm(t1, t0, 0x07060302u);
  r.z = __builtin_amdgcn_perm(t3, t2, 0x05040100u);
  r.w = __builtin_amdgcn_perm(t3, t2, 0x07060302u);
  return __builtin_bit_cast(bf16x8, r);
}

__device__ __forceinline__ bf16x8 decode8(uint4 p) { return decode4(pack4(p)); }

#define MFMA16(a_, b_, c_) __builtin_amdgcn_mfma_f32_16x16x32_bf16(a_, b_, c_, 0, 0, 0)

__global__ __launch_bounds__(NT, 2) void fp4gemm_dual_kernel(
    const ushort_t* __restrict__ xsrc,    // bf16 x [128,4096] (ws)
    const int*  __restrict__ wq,          // [N, K/2] packed
    const float* __restrict__ scale,      // [N]
    const float* __restrict__ bias,       // [N]
    float* __restrict__ out) {            // [M, N]
  __shared__ __align__(16) uint8_t lds[LDS_SZ];

  const int t   = threadIdx.x;
  const int w   = t >> 6;                 // wave 0..3 (m-strip w*32..+31)
  const int l   = t & 63;
  const int l16 = l & 15;
  const int lq  = l >> 4;

  // bijective XCD swizzle (512 % 8 == 0): consecutive-XCD blocks share A/B
  const int bid = blockIdx.x;
  const int n0  = ((bid & 7) * 64 + (bid >> 3)) * 32;

  // staging geometry: 256 thr x 16B = 4KB per gl16 round (32 rows x 128B)
  const int srow = t >> 3;                // 0..31
  const int scol = (t & 7) * 16;          // byte col 0..112
  const int scbs = scol ^ ((srow & 7) << 4);   // pre-swizzled A source col
  // B compact write: row srow (0..31), k-unit (t&7), XOR-swizzled
  const int bwro = srow * 32 + (((t & 7) ^ ((srow >> 2) & 3)) << 2);

  const uint8_t* xb  = (const uint8_t*)xsrc;  // bf16 row = 8192 B
  const uint8_t* wqb = (const uint8_t*)wq;    // int32 row = 8192 B

  uint4 rqe[2], rqo[2];                   // B packed regs (phase-parity sets)

#define ISSUE_A(p_, c_) do { \
  _Pragma("unroll") \
  for (int tau_ = 0; tau_ < 2; ++tau_) { \
    const size_t kb_ = (size_t)(2 * (p_) + tau_) * 128; \
    _Pragma("unroll") \
    for (int i_ = 0; i_ < 4; ++i_) \
      gl16(xb + (size_t)(i_ * 32 + srow) * 8192 + kb_ + scbs, \
           lds + ABASE(c_) + tau_ * 16384 + i_ * 4096 + w * 1024); \
  } \
} while (0)

#define ISSUE_B(p_, s_) do { \
  _Pragma("unroll") \
  for (int tau_ = 0; tau_ < 2; ++tau_) \
    rq##s_[tau_] = *(const uint4*)(wqb + (size_t)(n0 + srow) * 8192 + \
                                   (size_t)(2 * (p_) + tau_) * 128 + (t & 7) * 16); \
} while (0)

#define DSW_B(c_, s_) do { \
  _Pragma("unroll") \
  for (int tau_ = 0; tau_ < 2; ++tau_) \
    *(unsigned*)(lds + BBASE(c_) + tau_ * 1024 + bwro) = pack4(rq##s_[tau_]); \
} while (0)

#define WAITV(N_) asm volatile("s_waitcnt vmcnt(" #N_ ")" ::: "memory")
#define BARRIER() do { \
  asm volatile("s_waitcnt lgkmcnt(0)" ::: "memory"); \
  __builtin_amdgcn_s_barrier(); \
  __builtin_amdgcn_sched_barrier(0); \
} while (0)

  f32x4 acc00 = {0,0,0,0}, acc01 = {0,0,0,0};
  f32x4 acc10 = {0,0,0,0}, acc11 = {0,0,0,0};

  const int swzB = (l16 >> 2) & 3;             // B read swizzle (same both ci)
  const int bq0  = l16 * 32;                   // B row l16; ci=1 -> +512
  const int aR0  = (w * 32 + l16) * 128;       // A row base; mi=1 -> +2048
  const int aSwz = (l16 & 7) << 4;             // A col swizzle (same both mi)

#define COMPUTE(c_) do { \
  _Pragma("unroll") \
  for (int tau_ = 0; tau_ < 2; ++tau_) { \
    const uint8_t* Ab_ = lds + ABASE(c_) + tau_ * 16384; \
    const uint8_t* Bb_ = lds + BBASE(c_) + tau_ * 1024; \
    _Pragma("unroll") \
    for (int ks_ = 0; ks_ < 2; ++ks_) { \
      const int u_ = ((ks_ * 4 + lq) ^ swzB) << 2; \
      unsigned q0_ = *(const unsigned*)(Bb_ + bq0 + u_); \
      unsigned q1_ = *(const unsigned*)(Bb_ + bq0 + 512 + u_); \
      bf16x8 b0_ = decode4(q0_); \
      bf16x8 b1_ = decode4(q1_); \
      const int cS_ = ((ks_ * 64 + lq * 16) ^ aSwz); \
      bf16x8 a0_ = *(const bf16x8*)(Ab_ + aR0 + cS_); \
      bf16x8 a1_ = *(const bf16x8*)(Ab_ + aR0 + 2048 + cS_); \
      acc00 = MFMA16(a0_, b0_, acc00); \
      acc01 = MFMA16(a0_, b1_, acc01); \
      acc10 = MFMA16(a1_, b0_, acc10); \
      acc11 = MFMA16(a1_, b1_, acc11); \
    } \
  } \
} while (0)

// phase bodies (p compile-time parity; buffers/reg-sets by parity)
#define BODY_EVEN(p_) do { \
  WAITV(0); BARRIER(); \
  DSW_B(1, o); ISSUE_A((p_) + 1, 1); ISSUE_B((p_) + 2, e); \
  COMPUTE(0); \
} while (0)
#define BODY_ODD(p_) do { \
  WAITV(0); BARRIER(); \
  DSW_B(0, e); ISSUE_A((p_) + 1, 0); ISSUE_B((p_) + 2, o); \
  COMPUTE(1); \
} while (0)

  // ---- prologue ----
  ISSUE_B(0, e);                 // 2 loads
  ISSUE_A(0, 0);                 // 8 gl16
  WAITV(8);                      // B(ph0) retired (8 newer = the gl16s)
  DSW_B(0, e);                   // compact B for phase 0 into buf0
  ISSUE_B(1, o);
  // ---- phases 0..29 ----
  for (int j = 0; j < 15; ++j) {
    BODY_EVEN(2 * j);
    BODY_ODD(2 * j + 1);
  }
  // ---- tail ----
  // phase 30 (even): stage phase 31, no B(ph32)
  WAITV(0); BARRIER();
  DSW_B(1, o); ISSUE_A(31, 1);
  COMPUTE(0);
  // phase 31 (odd)
  WAITV(0); BARRIER();
  COMPUTE(1);

  // ---- epilogue: scale, bias, exact GELU ----
#pragma unroll
  for (int ci = 0; ci < 2; ++ci) {
    const int ngc = n0 + ci * 16 + l16;
    const float s  = scale[ngc];
    const float bb = bias[ngc];
    f32x4 v0 = ci ? acc01 : acc00;
    f32x4 v1 = ci ? acc11 : acc10;
#pragma unroll
    for (int mi = 0; mi < 2; ++mi) {
      f32x4 vv = mi ? v1 : v0;
#pragma unroll
      for (int j = 0; j < 4; ++j) {
        int m = w * 32 + mi * 16 + lq * 4 + j;
        float y = vv[j] * s + bb;
        float g = 0.5f * y * (1.0f + erff(y * 0.70710678118654752f));
        out[(size_t)m * N_DIM + ngc] = g;
      }
    }
  }
#undef ISSUE_A
#undef ISSUE_B
#undef DSW_B
#undef WAITV
#undef BARRIER
#undef COMPUTE
#undef BODY_EVEN
#undef BODY_ODD
}

// Fallback (ws too small): full-K, fp32-x inline, simple 2-buffer pipeline.
__global__ __launch_bounds__(512) void fp4gemm_fallback_kernel(
    const float* __restrict__ x, const int* __restrict__ wq,
    const float* __restrict__ scale, const float* __restrict__ bias,
    float* __restrict__ out) {
  __shared__ __align__(16) uint8_t lds[49152];
  const int t = threadIdx.x, w = t >> 6, l = t & 63;
  const int l16 = l & 15, lq = l >> 4, mq = w >> 1, nh = w & 1;
  const int n0 = (int)blockIdx.x * 64;
  const int srow = t >> 3, scol = (t & 7) * 16, sswz = (srow & 7) << 4;
  const int bwr = srow * 128 + (scol ^ sswz);
  const uint8_t* wqb = (const uint8_t*)wq;
  f32x4 acc00 = {0,0,0,0}, acc01 = {0,0,0,0};
  f32x4 acc10 = {0,0,0,0}, acc11 = {0,0,0,0};
  const int aR0 = (mq * 32 + l16) * 128;
  const int bR0 = (nh * 32 + l16) * 128;
  const int cB  = (lq << 4) ^ ((l16 & 7) << 4);
  for (int kt = 0; kt < 64; ++kt) {
    __syncthreads();
    int bb = kt & 1;
#pragma unroll
    for (int i = 0; i < 2; ++i) {
      const float* xf = x + (size_t)(i * 64 + srow) * K_DIM + (size_t)kt * 64 + (scol >> 1);
      float4 v0 = *(const float4*)(xf);
      float4 v1 = *(const float4*)(xf + 4);
      uint4 pk = make_uint4(f2b_bits(v0.x) | (f2b_bits(v0.y) << 16),
                            f2b_bits(v0.z) | (f2b_bits(v0.w) << 16),
                            f2b_bits(v1.x) | (f2b_bits(v1.y) << 16),
                            f2b_bits(v1.z) | (f2b_bits(v1.w) << 16));
      *(uint4*)(lds + bb * 16384 + (size_t)(i * 64 + srow) * 128 + (scol ^ sswz)) = pk;
    }
    {
      uint4 pv = *(const uint4*)(wqb + (size_t)(n0 + srow) * 8192 + (size_t)kt * 128 + scol);
      *(bf16x8*)(lds + 32768 + bb * 8192 + bwr) = decode8(pv);
    }
    __syncthreads();
    {
      const uint8_t* Ab_ = lds + bb * 16384;
      const uint8_t* Bb_ = lds + 32768 + bb * 8192;
#pragma unroll
      for (int ks = 0; ks < 2; ++ks) {
        const int cS = (ks << 6) ^ cB;
        bf16x8 a0 = *(const bf16x8*)(Ab_ + aR0 + cS);
        bf16x8 a1 = *(const bf16x8*)(Ab_ + aR0 + 2048 + cS);
        bf16x8 b0 = *(const bf16x8*)(Bb_ + bR0 + cS);
        bf16x8 b1 = *(const bf16x8*)(Bb_ + bR0 + 2048 + cS);
        acc00 = MFMA16(a0, b0, acc00);
        acc01 = MFMA16(a0, b1, acc01);
        acc10 = MFMA16(a1, b0, acc10);
        acc11 = MFMA16(a1, b1, acc11);
      }
    }
  }
#pragma unroll
  for (int c = 0; c < 2; ++c) {
    const int ngc = n0 + nh * 32 + c * 16 + l16;
    const float s = scale[ngc];
    const float bv = bias[ngc];
    f32x4 v0 = c ? acc01 : acc00;
    f32x4 v1 = c ? acc11 : acc10;
#pragma unroll
    for (int fr = 0; fr < 2; ++fr) {
      f32x4 vv = fr ? v1 : v0;
#pragma unroll
      for (int j = 0; j < 4; ++j) {
        int m = mq * 32 + fr * 16 + lq * 4 + j;
        float y = vv[j] * s + bv;
        out[(size_t)m * N_DIM + ngc] =
            0.5f * y * (1.0f + erff(y * 0.70710678118654752f));
      }
    }
  }
}

extern "C" void kernel_launch(void* const* d_in, const int* in_sizes, int n_in,
                              void* d_out, int out_size, void* d_ws, size_t ws_size,
                              hipStream_t stream) {
  const float* x     = (const float*)d_in[0];
  const int*   wq    = (const int*)d_in[1];
  const float* scale = (const float*)d_in[2];
  const float* bias  = (const float*)d_in[3];
  float* out = (float*)d_out;

  const size_t xb_bytes = (size_t)M_DIM * K_DIM * 2;   // 1 MB
  if (ws_size >= xb_bytes) {
    ushort_t* xb = (ushort_t*)d_ws;
    convert_x_kernel<<<(M_DIM * K_DIM) / (256 * 4), 256, 0, stream>>>(x, xb);
    fp4gemm_dual_kernel<<<NBLK, NT, 0, stream>>>(xb, wq, scale, bias, out);
  } else {
    fp4gemm_fallback_kernel<<<N_DIM / 64, 512, 0, stream>>>(
        x, wq, scale, bias, out);
  }
}

// Round 12
// 47.364 us; speedup vs baseline: 2.1549x; 1.2096x over previous
//
#include <hip/hip_runtime.h>
#include <stdint.h>

// FusedFP4Linear: out = gelu(x @ dequant(w_fp4)^T + bias)
// M=128, K=4096, N=16384. Weights [N, K/2] int32, low byte = two FP4 nibbles
// (hi nibble = even k, lo nibble = odd k).
// R12: R5 structure (BN=64, 8 waves, gl16 A staging, B global->reg->decode-
// once->LDS, 4 tile-bufs, 96KB LDS) with HALVED barrier frequency: one
// WAITV+s_barrier per 2-tile phase (32 barriers vs 64), B-regs 6 slots
// (3 phases deep), FIFO-retraced waits (prologue 8; steady 2; tail 0/0),
// and s_setprio(1) around each 16-MFMA phase compute (T5).

#define M_DIM 128
#define K_DIM 4096
#define N_DIM 16384
#define BN    64
#define BK    64
#define NK    (K_DIM/BK)       // 64 tiles = 32 phases
#define NT    512              // 8 waves
#define NBLK  (N_DIM/BN)       // 256

#define AOFF(b) ((b)*16384)             // 4 x 16KB A tile-bufs
#define BOFF(b) (65536 + (b)*8192)      // 4 x 8KB decoded-B tile-bufs
#define LDS_SZ  98304

typedef __attribute__((ext_vector_type(8))) __bf16 bf16x8;
typedef __attribute__((ext_vector_type(4))) float  f32x4;
typedef unsigned short ushort_t;

__device__ __forceinline__ unsigned f2b_bits(float f) {
  unsigned u = __builtin_bit_cast(unsigned, f);
  u += 0x7FFFu + ((u >> 16) & 1u);   // RNE
  return u >> 16;
}

__global__ __launch_bounds__(256) void convert_x_kernel(
    const float* __restrict__ x, ushort_t* __restrict__ xb) {
  int i = (blockIdx.x * blockDim.x + threadIdx.x) * 4;
  float4 v = *(const float4*)(x + i);
  ushort4 p;
  p.x = (ushort_t)f2b_bits(v.x);
  p.y = (ushort_t)f2b_bits(v.y);
  p.z = (ushort_t)f2b_bits(v.z);
  p.w = (ushort_t)f2b_bits(v.w);
  *(ushort4*)(xb + i) = p;
}

__device__ __forceinline__ void gl16(const void* g, void* l) {
  __builtin_amdgcn_global_load_lds(
      (const __attribute__((address_space(1))) void*)g,
      (__attribute__((address_space(3))) void*)l, 16, 0, 0);
}

// 4 packed int32 (low bytes) -> 8 bf16 (k-order: b0.hi, b0.lo, b1.hi, ...)
__device__ __forceinline__ bf16x8 decode8(uint4 p) {
  unsigned u01 = __builtin_amdgcn_perm(p.y, p.x, 0x04000400u);
  unsigned u23 = __builtin_amdgcn_perm(p.w, p.z, 0x04000400u);
  unsigned q   = __builtin_amdgcn_perm(u23, u01, 0x05040100u);  // [x0,y0,z0,w0]
  unsigned e  = (q >> 4) & 0x0F0F0F0Fu;
  unsigned o  = q & 0x0F0F0F0Fu;
  unsigned em = e & 0x07070707u, om = o & 0x07070707u;
  unsigned elo = __builtin_amdgcn_perm(0xC0804000u, 0xC0800000u, em);
  unsigned ehi = __builtin_amdgcn_perm(0x40404040u, 0x3F3F3F00u, em);
  unsigned olo = __builtin_amdgcn_perm(0xC0804000u, 0xC0800000u, om);
  unsigned ohi = __builtin_amdgcn_perm(0x40404040u, 0x3F3F3F00u, om);
  ehi |= (e & 0x08080808u) << 4;
  ohi |= (o & 0x08080808u) << 4;
  unsigned t0 = __builtin_amdgcn_perm(ehi, elo, 0x05010400u);
  unsigned t1 = __builtin_amdgcn_perm(ohi, olo, 0x05010400u);
  unsigned t2 = __builtin_amdgcn_perm(ehi, elo, 0x07030602u);
  unsigned t3 = __builtin_amdgcn_perm(ohi, olo, 0x07030602u);
  uint4 r;
  r.x = __builtin_amdgcn_perm(t1, t0, 0x05040100u);
  r.y = __builtin_amdgcn_perm(t1, t0, 0x07060302u);
  r.z = __builtin_amdgcn_perm(t3, t2, 0x05040100u);
  r.w = __builtin_amdgcn_perm(t3, t2, 0x07060302u);
  return __builtin_bit_cast(bf16x8, r);
}

#define MFMA16(a_, b_, c_) __builtin_amdgcn_mfma_f32_16x16x32_bf16(a_, b_, c_, 0, 0, 0)

__global__ __launch_bounds__(NT) void fp4gemm_kernel(
    const ushort_t* __restrict__ xsrc,    // bf16 x [128,4096] (ws)
    const int*  __restrict__ wq,          // [N, K/2] packed
    const float* __restrict__ scale,      // [N]
    const float* __restrict__ bias,       // [N]
    float* __restrict__ out) {            // [M, N]
  __shared__ __align__(16) uint8_t lds[LDS_SZ];

  const int t   = threadIdx.x;
  const int w   = t >> 6;                 // wave 0..7
  const int l   = t & 63;
  const int l16 = l & 15;
  const int lq  = l >> 4;
  const int mq  = w >> 1;                 // 0..3: rows mq*32..+31
  const int nh  = w & 1;                  // 0..1: cols nh*32..+31

  // bijective XCD swizzle (256 % 8 == 0)
  const int bid = blockIdx.x;
  const int n0  = ((bid & 7) * 32 + (bid >> 3)) * BN;

  // staging geometry: 512 thr x 16B = 8KB = 64 rows x 128B per round
  const int srow = t >> 3;                // 0..63
  const int scol = (t & 7) * 16;          // byte col 0..112
  const int sswz = (srow & 7) << 4;
  const int scbs = scol ^ sswz;           // pre-swizzled A source col
  const int bwr  = srow * 128 + (scol ^ sswz);  // B decoded LDS write off

  const uint8_t* xb  = (const uint8_t*)xsrc;  // bf16 row = 8192 B
  const uint8_t* wqb = (const uint8_t*)wq;    // int32 row = 8192 B

  uint4 rb0, rb1, rb2, rb3, rb4, rb5;     // B packed reg slots (tile k % 6)

#define ISSUE_A1(k_, b_) do { \
  gl16(xb + (size_t)(srow) * 8192 + (size_t)(k_) * 128 + scbs, \
       lds + AOFF(b_) + w * 1024); \
  gl16(xb + (size_t)(64 + srow) * 8192 + (size_t)(k_) * 128 + scbs, \
       lds + AOFF(b_) + 8192 + w * 1024); \
} while (0)

#define ISSUE_B1(k_, s_) do { \
  rb##s_ = *(const uint4*)(wqb + (size_t)(n0 + srow) * 8192 + \
                           (size_t)(k_) * 128 + scol); \
} while (0)

#define DEC1(s_, b_) do { \
  *(bf16x8*)(lds + BOFF(b_) + bwr) = decode8(rb##s_); \
} while (0)

#define WAITV(N_) asm volatile("s_waitcnt vmcnt(" #N_ ")" ::: "memory")
#define BARRIER() do { \
  asm volatile("s_waitcnt lgkmcnt(0)" ::: "memory"); \
  __builtin_amdgcn_s_barrier(); \
  __builtin_amdgcn_sched_barrier(0); \
} while (0)

  f32x4 acc00 = {0,0,0,0}, acc01 = {0,0,0,0};
  f32x4 acc10 = {0,0,0,0}, acc11 = {0,0,0,0};

  const int aR0 = (mq * 32 + l16) * 128;       // +2048 for fr=1
  const int bR0 = (nh * 32 + l16) * 128;       // +2048 for c=1
  const int cB  = (lq << 4) ^ ((l16 & 7) << 4);

#define COMPUTE(b_) do { \
  const uint8_t* Ab_ = lds + AOFF(b_); \
  const uint8_t* Bb_ = lds + BOFF(b_); \
  _Pragma("unroll") \
  for (int ks_ = 0; ks_ < 2; ++ks_) { \
    const int cS_ = (ks_ << 6) ^ cB; \
    bf16x8 a0_ = *(const bf16x8*)(Ab_ + aR0 + cS_); \
    bf16x8 a1_ = *(const bf16x8*)(Ab_ + aR0 + 2048 + cS_); \
    bf16x8 b0_ = *(const bf16x8*)(Bb_ + bR0 + cS_); \
    bf16x8 b1_ = *(const bf16x8*)(Bb_ + bR0 + 2048 + cS_); \
    acc00 = MFMA16(a0_, b0_, acc00); \
    acc01 = MFMA16(a0_, b1_, acc01); \
    acc10 = MFMA16(a1_, b0_, acc10); \
    acc11 = MFMA16(a1_, b1_, acc11); \
  } \
} while (0)

// Phase body (tiles k_,k_+1 in bufs ca_,cb_). Decodes tiles k_+2,k_+3
// (slots sa_,sb_) into bufs ba_,bb_; stages A(k_+2,k_+3) into ba_,bb_;
// issues B(k_+6,k_+7) into slots ia_,ib_. One barrier per phase.
#define BODY(k_, ca_, cb_, ba_, bb_, sa_, sb_, ia_, ib_, W_) do { \
  WAITV(W_); \
  BARRIER(); \
  DEC1(sa_, ba_); DEC1(sb_, bb_); \
  ISSUE_A1((k_) + 2, ba_); ISSUE_A1((k_) + 3, bb_); \
  ISSUE_B1((k_) + 6, ia_); ISSUE_B1((k_) + 7, ib_); \
  __builtin_amdgcn_s_setprio(1); \
  COMPUTE(ca_); COMPUTE(cb_); \
  __builtin_amdgcn_s_setprio(0); \
} while (0)

// 6-phase steady group starting at even tile k0_ (phase p = k0_/2 ≡ 0 mod 6)
#define GROUP6(k0_) do { \
  BODY((k0_)+0,  0,1, 2,3, 2,3, 0,1, 2); \
  BODY((k0_)+2,  2,3, 0,1, 4,5, 2,3, 2); \
  BODY((k0_)+4,  0,1, 2,3, 0,1, 4,5, 2); \
  BODY((k0_)+6,  2,3, 0,1, 2,3, 0,1, 2); \
  BODY((k0_)+8,  0,1, 2,3, 4,5, 2,3, 2); \
  BODY((k0_)+10, 2,3, 0,1, 0,1, 4,5, 2); \
} while (0)

  // ---- prologue (FIFO: B{0,1},A{0,1}x4,B{2,3},B{4,5} -> retire B{0,1}=8) --
  ISSUE_B1(0, 0); ISSUE_B1(1, 1);
  ISSUE_A1(0, 0); ISSUE_A1(1, 1);
  ISSUE_B1(2, 2); ISSUE_B1(3, 3);
  ISSUE_B1(4, 4); ISSUE_B1(5, 5);
  WAITV(8);                        // B{0,1} retired
  DEC1(0, 0); DEC1(1, 1);          // decoded B for phase 0 (lgkm at barrier)

  // ---- steady: phases 0..23 (tiles 0..47) ----
  for (int j = 0; j < 4; ++j) GROUP6(12 * j);

  // ---- peel phases 24..28 (tiles 48..57), steady-shaped ----
  BODY(48, 0,1, 2,3, 2,3, 0,1, 2);
  BODY(50, 2,3, 0,1, 4,5, 2,3, 2);
  BODY(52, 0,1, 2,3, 0,1, 4,5, 2);
  BODY(54, 2,3, 0,1, 2,3, 0,1, 2);
  BODY(56, 0,1, 2,3, 4,5, 2,3, 2);
  // ---- phase 29 (tiles 58,59): no B issue ----
  WAITV(2); BARRIER();
  DEC1(0, 0); DEC1(1, 1);
  ISSUE_A1(60, 0); ISSUE_A1(61, 1);
  __builtin_amdgcn_s_setprio(1); COMPUTE(2); COMPUTE(3);
  __builtin_amdgcn_s_setprio(0);
  // ---- phase 30 (tiles 60,61) ----
  WAITV(0); BARRIER();
  DEC1(2, 2); DEC1(3, 3);
  ISSUE_A1(62, 2); ISSUE_A1(63, 3);
  __builtin_amdgcn_s_setprio(1); COMPUTE(0); COMPUTE(1);
  __builtin_amdgcn_s_setprio(0);
  // ---- phase 31 (tiles 62,63) ----
  WAITV(0); BARRIER();
  __builtin_amdgcn_s_setprio(1); COMPUTE(2); COMPUTE(3);
  __builtin_amdgcn_s_setprio(0);

  // ---- epilogue: scale, bias, exact GELU ----
#pragma unroll
  for (int c = 0; c < 2; ++c) {
    const int ngc = n0 + nh * 32 + c * 16 + l16;
    const float s  = scale[ngc];
    const float bb = bias[ngc];
    f32x4 v0 = c ? acc01 : acc00;
    f32x4 v1 = c ? acc11 : acc10;
#pragma unroll
    for (int fr = 0; fr < 2; ++fr) {
      f32x4 vv = fr ? v1 : v0;
#pragma unroll
      for (int j = 0; j < 4; ++j) {
        int m = mq * 32 + fr * 16 + lq * 4 + j;
        float y = vv[j] * s + bb;
        float g = 0.5f * y * (1.0f + erff(y * 0.70710678118654752f));
        out[(size_t)m * N_DIM + ngc] = g;
      }
    }
  }
#undef ISSUE_A1
#undef ISSUE_B1
#undef DEC1
#undef WAITV
#undef BARRIER
#undef COMPUTE
#undef BODY
#undef GROUP6
}

// Fallback (ws too small): full-K, fp32-x inline, simple 2-buffer pipeline.
__global__ __launch_bounds__(NT) void fp4gemm_fallback_kernel(
    const float* __restrict__ x, const int* __restrict__ wq,
    const float* __restrict__ scale, const float* __restrict__ bias,
    float* __restrict__ out) {
  __shared__ __align__(16) uint8_t lds[49152];
  const int t = threadIdx.x, w = t >> 6, l = t & 63;
  const int l16 = l & 15, lq = l >> 4, mq = w >> 1, nh = w & 1;
  const int n0 = (int)blockIdx.x * 64;
  const int srow = t >> 3, scol = (t & 7) * 16, sswz = (srow & 7) << 4;
  const int bwr = srow * 128 + (scol ^ sswz);
  const uint8_t* wqb = (const uint8_t*)wq;
  f32x4 acc00 = {0,0,0,0}, acc01 = {0,0,0,0};
  f32x4 acc10 = {0,0,0,0}, acc11 = {0,0,0,0};
  const int aR0 = (mq * 32 + l16) * 128;
  const int bR0 = (nh * 32 + l16) * 128;
  const int cB  = (lq << 4) ^ ((l16 & 7) << 4);
  for (int kt = 0; kt < 64; ++kt) {
    __syncthreads();
    int bb = kt & 1;
#pragma unroll
    for (int i = 0; i < 2; ++i) {
      const float* xf = x + (size_t)(i * 64 + srow) * K_DIM + (size_t)kt * 64 + (scol >> 1);
      float4 v0 = *(const float4*)(xf);
      float4 v1 = *(const float4*)(xf + 4);
      uint4 pk = make_uint4(f2b_bits(v0.x) | (f2b_bits(v0.y) << 16),
                            f2b_bits(v0.z) | (f2b_bits(v0.w) << 16),
                            f2b_bits(v1.x) | (f2b_bits(v1.y) << 16),
                            f2b_bits(v1.z) | (f2b_bits(v1.w) << 16));
      *(uint4*)(lds + bb * 16384 + (size_t)(i * 64 + srow) * 128 + (scol ^ sswz)) = pk;
    }
    {
      uint4 pv = *(const uint4*)(wqb + (size_t)(n0 + srow) * 8192 + (size_t)kt * 128 + scol);
      *(bf16x8*)(lds + 32768 + bb * 8192 + bwr) = decode8(pv);
    }
    __syncthreads();
    {
      const uint8_t* Ab_ = lds + bb * 16384;
      const uint8_t* Bb_ = lds + 32768 + bb * 8192;
#pragma unroll
      for (int ks = 0; ks < 2; ++ks) {
        const int cS = (ks << 6) ^ cB;
        bf16x8 a0 = *(const bf16x8*)(Ab_ + aR0 + cS);
        bf16x8 a1 = *(const bf16x8*)(Ab_ + aR0 + 2048 + cS);
        bf16x8 b0 = *(const bf16x8*)(Bb_ + bR0 + cS);
        bf16x8 b1 = *(const bf16x8*)(Bb_ + bR0 + 2048 + cS);
        acc00 = MFMA16(a0, b0, acc00);
        acc01 = MFMA16(a0, b1, acc01);
        acc10 = MFMA16(a1, b0, acc10);
        acc11 = MFMA16(a1, b1, acc11);
      }
    }
  }
#pragma unroll
  for (int c = 0; c < 2; ++c) {
    const int ngc = n0 + nh * 32 + c * 16 + l16;
    const float s = scale[ngc];
    const float bv = bias[ngc];
    f32x4 v0 = c ? acc01 : acc00;
    f32x4 v1 = c ? acc11 : acc10;
#pragma unroll
    for (int fr = 0; fr < 2; ++fr) {
      f32x4 vv = fr ? v1 : v0;
#pragma unroll
      for (int j = 0; j < 4; ++j) {
        int m = mq * 32 + fr * 16 + lq * 4 + j;
        float y = vv[j] * s + bv;
        out[(size_t)m * N_DIM + ngc] =
            0.5f * y * (1.0f + erff(y * 0.70710678118654752f));
      }
    }
  }
}

extern "C" void kernel_launch(void* const* d_in, const int* in_sizes, int n_in,
                              void* d_out, int out_size, void* d_ws, size_t ws_size,
                              hipStream_t stream) {
  const float* x     = (const float*)d_in[0];
  const int*   wq    = (const int*)d_in[1];
  const float* scale = (const float*)d_in[2];
  const float* bias  = (const float*)d_in[3];
  float* out = (float*)d_out;

  const size_t xb_bytes = (size_t)M_DIM * K_DIM * 2;   // 1 MB
  if (ws_size >= xb_bytes) {
    ushort_t* xb = (ushort_t*)d_ws;
    convert_x_kernel<<<(M_DIM * K_DIM) / (256 * 4), 256, 0, stream>>>(x, xb);
    fp4gemm_kernel<<<NBLK, NT, 0, stream>>>(xb, wq, scale, bias, out);
  } else {
    fp4gemm_fallback_kernel<<<N_DIM / 64, NT, 0, stream>>>(
        x, wq, scale, bias, out);
  }
}